// Round 2
// baseline (17765.918 us; speedup 1.0000x reference)
//
#include <hip/hip_runtime.h>
#include <hip/hip_bf16.h>

namespace {

constexpr int NN = 20000;   // nodes
constexpr int TT = 16;      // tokens per node
constexpr int DD = 256;     // hidden dim
constexpr int EE = 320000;  // edges
constexpr int BB = 64;      // graphs
constexpr int NLAY = 3;
constexpr int NGRUS = 4;
constexpr int D3 = 768;     // 3*D

__device__ __forceinline__ float us2f(unsigned short u){
  union { unsigned int i; float f; } v; v.i = ((unsigned int)u) << 16; return v.f;
}
__device__ __forceinline__ unsigned short f2us(float f){
  union { float f; unsigned int i; } v; v.f = f;
  unsigned int r = v.i + 0x7fff + ((v.i >> 16) & 1);   // RNE
  return (unsigned short)(r >> 16);
}

// ---------------- init: zero/one fills ----------------
__global__ void k_init(int* __restrict__ deg, int* __restrict__ cursor,
                       int* __restrict__ counts, int* __restrict__ nmask,
                       float* __restrict__ out){
  int i = blockIdx.x*256 + threadIdx.x;
  if (i < NN){ deg[i] = 0; cursor[i] = 0; nmask[i] = 1; }
  if (i < BB) counts[i] = 0;
  if (i < BB*DD) out[i] = 0.f;
}

// ---------------- embedding mean-pool (f32 in -> bf16 h) ----------------
__global__ void k_embed(const int* __restrict__ xt, const float* __restrict__ emb,
                        unsigned short* __restrict__ h){
  int n = blockIdx.x; int d = threadIdx.x;
  __shared__ int toks[TT];
  if (threadIdx.x < TT) toks[threadIdx.x] = xt[n*TT + threadIdx.x];
  __syncthreads();
  float acc = 0.f; int cnt = 0;
  #pragma unroll
  for (int t = 0; t < TT; ++t){
    int tk = toks[t];
    if (tk != 0){ ++cnt; acc += emb[(size_t)tk*DD + d]; }
  }
  h[(size_t)n*DD + d] = f2us(acc / (float)(cnt > 0 ? cnt : 1));
}

// ---------------- WF[lg] = W[lg] @ Wih[l]^T : out[k][j] = sum_d W[k][d]*Wih[j][d] ----------------
__global__ __launch_bounds__(256) void k_wf(const float* __restrict__ W,
                                            const float* __restrict__ Wih,
                                            float* __restrict__ WF){
  int lg = blockIdx.z; int l = lg / NGRUS;
  const float* A  = W   + (size_t)lg*DD*DD;   // [256][256]
  const float* Bm = Wih + (size_t)l*D3*DD;    // [768][256]
  float* out = WF + (size_t)lg*DD*D3;         // [256][768]
  int k0 = blockIdx.y*64, j0 = blockIdx.x*64;
  __shared__ float sA[16][68], sB[16][68];
  int tid = threadIdx.x, ty = tid/16, tx = tid%16;
  float acc[4][4] = {};
  int m = tid >> 2, dg = (tid & 3)*4;
  for (int d0 = 0; d0 < DD; d0 += 16){
    float4 ua = *reinterpret_cast<const float4*>(A  + (size_t)(k0+m)*DD + d0+dg);
    float4 ub = *reinterpret_cast<const float4*>(Bm + (size_t)(j0+m)*DD + d0+dg);
    __syncthreads();
    sA[dg+0][m]=ua.x; sA[dg+1][m]=ua.y; sA[dg+2][m]=ua.z; sA[dg+3][m]=ua.w;
    sB[dg+0][m]=ub.x; sB[dg+1][m]=ub.y; sB[dg+2][m]=ub.z; sB[dg+3][m]=ub.w;
    __syncthreads();
    #pragma unroll
    for (int dd = 0; dd < 16; ++dd){
      float a[4], b[4];
      #pragma unroll
      for (int i=0;i<4;++i) a[i] = sA[dd][ty*4+i];
      #pragma unroll
      for (int j=0;j<4;++j) b[j] = sB[dd][tx*4+j];
      #pragma unroll
      for (int i=0;i<4;++i)
        #pragma unroll
        for (int j=0;j<4;++j) acc[i][j] += a[i]*b[j];
    }
  }
  for (int i=0;i<4;++i){
    int k = k0 + ty*4 + i;
    for (int j=0;j<4;++j) out[(size_t)k*D3 + j0 + tx*4 + j] = acc[i][j];
  }
}

// ---------------- CSR build ----------------
__global__ void k_deg(const int* __restrict__ dst, int* __restrict__ deg){
  int e = blockIdx.x*256 + threadIdx.x; if (e < EE) atomicAdd(&deg[dst[e]], 1);
}
__global__ void k_scan(const int* __restrict__ deg, int* __restrict__ offs){
  __shared__ int part[1024];
  int t = threadIdx.x; const int CH = 20;  // 1024*20 >= 20000
  int base = t*CH; int s = 0;
  for (int i = 0; i < CH; ++i){ int idx = base+i; if (idx < NN) s += deg[idx]; }
  part[t] = s; __syncthreads();
  for (int o = 1; o < 1024; o <<= 1){
    int v = part[t]; int add = (t >= o) ? part[t-o] : 0;
    __syncthreads(); part[t] = v + add; __syncthreads();
  }
  int run = (t > 0) ? part[t-1] : 0;
  for (int i = 0; i < CH; ++i){ int idx = base+i; if (idx < NN){ offs[idx] = run; run += deg[idx]; } }
  if (t == 1023) offs[NN] = run;
}
__global__ void k_fill_csr(const int* __restrict__ src, const int* __restrict__ dst,
                           const int* __restrict__ offs, int* __restrict__ cursor,
                           int* __restrict__ csr_src){
  int e = blockIdx.x*256 + threadIdx.x; if (e >= EE) return;
  int d = dst[e]; int pos = atomicAdd(&cursor[d], 1);
  csr_src[offs[d] + pos] = src[e];
}
__global__ void k_counts(const int* __restrict__ batch, int* __restrict__ counts){
  int n = blockIdx.x*256 + threadIdx.x; if (n < NN) atomicAdd(&counts[batch[n]], 1);
}
__global__ void k_starts(const int* __restrict__ counts, int* __restrict__ starts){
  if (threadIdx.x == 0){ int s = 0; for (int b = 0; b < BB; ++b){ starts[b] = s; s += counts[b]; } }
}

// ---------------- edge aggregation: agg[n] = sum_{e in in(n)} h[src[e]]  (dead h == 0) ----------------
__global__ void k_agg(const unsigned short* __restrict__ h, const int* __restrict__ offs,
                      const int* __restrict__ csr_src, unsigned short* __restrict__ agg){
  int n = blockIdx.x; int d = threadIdx.x;
  int s = offs[n], e = offs[n+1];
  __shared__ int ssrc[256];
  float acc = 0.f;
  for (int base = s; base < e; base += 256){
    int mcnt = min(256, e - base);
    __syncthreads();
    if (d < mcnt) ssrc[d] = csr_src[base + d];
    __syncthreads();
    for (int i = 0; i < mcnt; ++i)
      acc += us2f(h[(size_t)ssrc[i]*DD + d]);
  }
  agg[(size_t)n*DD + d] = f2us(acc);
}

// ---------------- fused GRU step: both GEMMs (all 3 gates) + elementwise update ----------------
// gi = agg @ WF (f32 weights), gh = h @ Whh^T (f32 weights); A-operands bf16.
__global__ __launch_bounds__(256) void k_gru(
    const unsigned short* __restrict__ Ag, const unsigned short* __restrict__ Ah,
    const float* __restrict__ WFl, const float* __restrict__ Whh,
    const float* __restrict__ bih, const float* __restrict__ bhh,
    const int* __restrict__ nmask, unsigned short* __restrict__ Hn, int do_relu){
  int r0 = blockIdx.x*64, cb = blockIdx.y*64;   // cb in {0,64,128,192}
  __shared__ float sAg[16][68], sAh[16][68];
  __shared__ float sW0[16][68], sW1[16][68], sW2[16][68];   // WF slices (r,z,n)
  __shared__ float sH0[16][68], sH1[16][68], sH2[16][68];   // Whh slices (r,z,n)
  int tid = threadIdx.x, ty = tid/16, tx = tid%16;
  int m = tid >> 2, kg4 = (tid & 3)*4;
  int kk16 = tid >> 4, jg4 = (tid & 15)*4;
  float aR[4][4] = {}, aZ[4][4] = {}, aNi[4][4] = {}, aNh[4][4] = {};
  for (int k0 = 0; k0 < DD; k0 += 16){
    int row = r0 + m;
    ushort4 a4 = make_ushort4(0,0,0,0), h4 = make_ushort4(0,0,0,0);
    if (row < NN){
      a4 = *reinterpret_cast<const ushort4*>(Ag + (size_t)row*DD + k0 + kg4);
      h4 = *reinterpret_cast<const ushort4*>(Ah + (size_t)row*DD + k0 + kg4);
    }
    float4 w0 = *reinterpret_cast<const float4*>(WFl + (size_t)(k0+kk16)*D3 +       cb + jg4);
    float4 w1 = *reinterpret_cast<const float4*>(WFl + (size_t)(k0+kk16)*D3 + 256 + cb + jg4);
    float4 w2 = *reinterpret_cast<const float4*>(WFl + (size_t)(k0+kk16)*D3 + 512 + cb + jg4);
    float4 q0 = *reinterpret_cast<const float4*>(Whh + (size_t)(      cb + m)*DD + k0 + kg4);
    float4 q1 = *reinterpret_cast<const float4*>(Whh + (size_t)(256 + cb + m)*DD + k0 + kg4);
    float4 q2 = *reinterpret_cast<const float4*>(Whh + (size_t)(512 + cb + m)*DD + k0 + kg4);
    __syncthreads();
    sAg[kg4+0][m]=us2f(a4.x); sAg[kg4+1][m]=us2f(a4.y); sAg[kg4+2][m]=us2f(a4.z); sAg[kg4+3][m]=us2f(a4.w);
    sAh[kg4+0][m]=us2f(h4.x); sAh[kg4+1][m]=us2f(h4.y); sAh[kg4+2][m]=us2f(h4.z); sAh[kg4+3][m]=us2f(h4.w);
    *reinterpret_cast<float4*>(&sW0[kk16][jg4]) = w0;
    *reinterpret_cast<float4*>(&sW1[kk16][jg4]) = w1;
    *reinterpret_cast<float4*>(&sW2[kk16][jg4]) = w2;
    sH0[kg4+0][m]=q0.x; sH0[kg4+1][m]=q0.y; sH0[kg4+2][m]=q0.z; sH0[kg4+3][m]=q0.w;
    sH1[kg4+0][m]=q1.x; sH1[kg4+1][m]=q1.y; sH1[kg4+2][m]=q1.z; sH1[kg4+3][m]=q1.w;
    sH2[kg4+0][m]=q2.x; sH2[kg4+1][m]=q2.y; sH2[kg4+2][m]=q2.z; sH2[kg4+3][m]=q2.w;
    __syncthreads();
    #pragma unroll
    for (int kk = 0; kk < 16; ++kk){
      float4 agv = *reinterpret_cast<const float4*>(&sAg[kk][ty*4]);
      float4 ahv = *reinterpret_cast<const float4*>(&sAh[kk][ty*4]);
      float4 b0 = *reinterpret_cast<const float4*>(&sW0[kk][tx*4]);
      float4 b1 = *reinterpret_cast<const float4*>(&sW1[kk][tx*4]);
      float4 b2 = *reinterpret_cast<const float4*>(&sW2[kk][tx*4]);
      float4 c0 = *reinterpret_cast<const float4*>(&sH0[kk][tx*4]);
      float4 c1 = *reinterpret_cast<const float4*>(&sH1[kk][tx*4]);
      float4 c2 = *reinterpret_cast<const float4*>(&sH2[kk][tx*4]);
      float A_[4]={agv.x,agv.y,agv.z,agv.w}, H_[4]={ahv.x,ahv.y,ahv.z,ahv.w};
      float B0[4]={b0.x,b0.y,b0.z,b0.w}, B1[4]={b1.x,b1.y,b1.z,b1.w}, B2[4]={b2.x,b2.y,b2.z,b2.w};
      float C0[4]={c0.x,c0.y,c0.z,c0.w}, C1[4]={c1.x,c1.y,c1.z,c1.w}, C2[4]={c2.x,c2.y,c2.z,c2.w};
      #pragma unroll
      for (int i=0;i<4;++i)
        #pragma unroll
        for (int j=0;j<4;++j){
          aR[i][j]  += A_[i]*B0[j] + H_[i]*C0[j];
          aZ[i][j]  += A_[i]*B1[j] + H_[i]*C1[j];
          aNi[i][j] += A_[i]*B2[j];
          aNh[i][j] += H_[i]*C2[j];
        }
    }
  }
  #pragma unroll
  for (int i=0;i<4;++i){
    int row = r0 + ty*4 + i;
    if (row >= NN) continue;
    int msk = nmask[row];
    #pragma unroll
    for (int j=0;j<4;++j){
      int col = cb + tx*4 + j;
      float r = 1.f/(1.f + expf(-(aR[i][j] + bih[col]       + bhh[col])));
      float z = 1.f/(1.f + expf(-(aZ[i][j] + bih[256+col]   + bhh[256+col])));
      float nn = tanhf(aNi[i][j] + bih[512+col] + r*(aNh[i][j] + bhh[512+col]));
      float ho = us2f(Ah[(size_t)row*DD + col]);
      float o = (1.f - z)*nn + z*ho;
      if (do_relu) o = fmaxf(o, 0.f);
      if (!msk) o = 0.f;   // dead nodes stay exactly 0 (matches reference observably)
      Hn[(size_t)row*DD + col] = f2us(o);
    }
  }
}

// ---------------- topk score ----------------
__global__ void k_score(const unsigned short* __restrict__ h, const float* __restrict__ p,
                        float* __restrict__ score){
  int wid = threadIdx.x >> 6, lane = threadIdx.x & 63;
  int n = blockIdx.x*4 + wid; if (n >= NN) return;
  ushort4 hu = *reinterpret_cast<const ushort4*>(h + (size_t)n*DD + lane*4);
  float4 pv = *reinterpret_cast<const float4*>(p + lane*4);
  float dot = us2f(hu.x)*pv.x + us2f(hu.y)*pv.y + us2f(hu.z)*pv.z + us2f(hu.w)*pv.w;
  float pp = pv.x*pv.x + pv.y*pv.y + pv.z*pv.z + pv.w*pv.w;
  for (int o = 32; o; o >>= 1){ dot += __shfl_down(dot, o); pp += __shfl_down(pp, o); }
  if (lane == 0) score[n] = tanhf(dot / sqrtf(pp));
}

// ---------------- per-graph topk selection (score desc, tie -> lower index) ----------------
__global__ void k_topk(const float* __restrict__ score, const int* __restrict__ starts,
                       const int* __restrict__ counts, int* __restrict__ nmask){
  int b = blockIdx.x; int st = starts[b]; int cnt = min(counts[b], 1024);
  __shared__ float sc[1024]; __shared__ int ired[256];
  int t = threadIdx.x;
  int myvalid = 0;
  for (int i = t; i < cnt; i += 256){
    int node = st + i; int v = nmask[node];
    sc[i] = v ? score[node] : -1e30f;
    myvalid += v;
  }
  ired[t] = myvalid; __syncthreads();
  for (int o = 128; o; o >>= 1){ if (t < o) ired[t] += ired[t+o]; __syncthreads(); }
  int nv = ired[0];
  int k = (4*nv + 4)/5;   // == ceil(0.8*nv) for these n
  __syncthreads();
  for (int i = t; i < cnt; i += 256){
    float si = sc[i]; int node = st + i; int keep = 0;
    if (si > -1e29f){
      int rank = 0;
      for (int j = 0; j < cnt; ++j){
        float sj = sc[j];
        rank += (sj > si) || (sj == si && j < i);
      }
      keep = (rank < k);
    }
    nmask[node] = keep;
  }
}

__global__ void k_scale(unsigned short* __restrict__ h, const float* __restrict__ score,
                        const int* __restrict__ nmask){
  int idx = blockIdx.x*256 + threadIdx.x;  // grid = NN blocks covers N*D
  int n = idx >> 8;
  unsigned short v = nmask[n] ? f2us(us2f(h[idx])*score[n]) : (unsigned short)0;
  h[idx] = v;
}

// ---------------- global attention per graph, accumulates into d_out (f32) ----------------
__global__ void k_att(const unsigned short* __restrict__ h, const float* __restrict__ gW,
                      const float* __restrict__ gb, const int* __restrict__ starts,
                      const int* __restrict__ counts, const int* __restrict__ nmask,
                      float* __restrict__ outacc){
  int b = blockIdx.x; int st = starts[b]; int cnt = min(counts[b], 1024);
  __shared__ float lg[1024]; __shared__ float red[256];
  int t = threadIdx.x, wid = t >> 6, lane = t & 63;
  float gbv = gb[0];
  for (int i = wid; i < cnt; i += 4){
    int node = st + i;
    ushort4 hu = *reinterpret_cast<const ushort4*>(h + (size_t)node*DD + lane*4);
    float4 wv = *reinterpret_cast<const float4*>(gW + lane*4);
    float dot = us2f(hu.x)*wv.x + us2f(hu.y)*wv.y + us2f(hu.z)*wv.z + us2f(hu.w)*wv.w;
    for (int o = 32; o; o >>= 1) dot += __shfl_down(dot, o);
    if (lane == 0) lg[i] = nmask[node] ? dot + gbv : -1e30f;
  }
  __syncthreads();
  float mx = -1e30f;
  for (int i = t; i < cnt; i += 256) mx = fmaxf(mx, lg[i]);
  red[t] = mx; __syncthreads();
  for (int o = 128; o; o >>= 1){ if (t < o) red[t] = fmaxf(red[t], red[t+o]); __syncthreads(); }
  mx = red[0]; __syncthreads();
  float se = 0.f;
  for (int i = t; i < cnt; i += 256){
    float e = (lg[i] > -1e29f) ? expf(lg[i] - mx) : 0.f;
    lg[i] = e; se += e;
  }
  red[t] = se; __syncthreads();
  for (int o = 128; o; o >>= 1){ if (t < o) red[t] += red[t+o]; __syncthreads(); }
  float denom = fmaxf(red[0], 1e-12f);
  __syncthreads();
  float a0=0.f,a1=0.f,a2=0.f,a3=0.f;
  int i = 0;
  for (; i + 4 <= cnt; i += 4){
    a0 += lg[i+0]*us2f(h[(size_t)(st+i+0)*DD + t]);
    a1 += lg[i+1]*us2f(h[(size_t)(st+i+1)*DD + t]);
    a2 += lg[i+2]*us2f(h[(size_t)(st+i+2)*DD + t]);
    a3 += lg[i+3]*us2f(h[(size_t)(st+i+3)*DD + t]);
  }
  for (; i < cnt; ++i) a0 += lg[i]*us2f(h[(size_t)(st+i)*DD + t]);
  outacc[(size_t)b*DD + t] += (a0+a1+a2+a3)/denom;
}

} // namespace

extern "C" void kernel_launch(void* const* d_in, const int* in_sizes, int n_in,
                              void* d_out, int out_size, void* d_ws, size_t ws_size,
                              hipStream_t stream){
  const int*   x_tokens = (const int*)d_in[0];
  const int*   e_src    = (const int*)d_in[1];
  const int*   e_dst    = e_src + EE;
  const int*   batch    = (const int*)d_in[2];
  const float* embed    = (const float*)d_in[3];
  const float* ggcW     = (const float*)d_in[4];
  const float* gWih     = (const float*)d_in[5];
  const float* gWhh     = (const float*)d_in[6];
  const float* gbih     = (const float*)d_in[7];
  const float* gbhh     = (const float*)d_in[8];
  const float* topkp    = (const float*)d_in[9];
  const float* gateW    = (const float*)d_in[10];
  const float* gateb    = (const float*)d_in[11];
  (void)in_sizes; (void)n_in; (void)out_size;
  float* out = (float*)d_out;

  char* ws = (char*)d_ws;
  size_t off = 0;
  auto carve = [&](size_t bytes)->char*{
    char* p = ws + off;
    off += (bytes + 255) & ~(size_t)255;
    return p;
  };
  unsigned short* h0  = (unsigned short*)carve((size_t)NN*DD*2);
  unsigned short* h1  = (unsigned short*)carve((size_t)NN*DD*2);
  unsigned short* agg = (unsigned short*)carve((size_t)NN*DD*2);
  float* WF      = (float*)carve((size_t)NLAY*NGRUS*DD*D3*4);
  float* score   = (float*)carve((size_t)NN*4);
  int* nmask     = (int*)carve((size_t)NN*4);
  int* deg       = (int*)carve((size_t)NN*4);
  int* cursor    = (int*)carve((size_t)NN*4);
  int* offs      = (int*)carve((size_t)(NN+1)*4);
  int* csr_src   = (int*)carve((size_t)EE*4);
  int* counts    = (int*)carve((size_t)BB*4);
  int* starts    = (int*)carve((size_t)BB*4);
  if (off > ws_size) return;  // ~42 MB total

  k_init<<<(NN+255)/256, 256, 0, stream>>>(deg, cursor, counts, nmask, out);
  k_embed<<<NN, DD, 0, stream>>>(x_tokens, embed, h0);
  k_wf<<<dim3(D3/64, DD/64, NLAY*NGRUS), 256, 0, stream>>>(ggcW, gWih, WF);
  k_deg<<<(EE+255)/256, 256, 0, stream>>>(e_dst, deg);
  k_scan<<<1, 1024, 0, stream>>>(deg, offs);
  k_fill_csr<<<(EE+255)/256, 256, 0, stream>>>(e_src, e_dst, offs, cursor, csr_src);
  k_counts<<<(NN+255)/256, 256, 0, stream>>>(batch, counts);
  k_starts<<<1, 64, 0, stream>>>(counts, starts);

  unsigned short* hc = h0; unsigned short* hn = h1;
  for (int l = 0; l < NLAY; ++l){
    const float* Whl  = gWhh + (size_t)l*D3*DD;
    const float* bihl = gbih + (size_t)l*D3;
    const float* bhhl = gbhh + (size_t)l*D3;
    for (int g = 0; g < NGRUS; ++g){
      const float* WFl = WF + (size_t)(l*NGRUS+g)*DD*D3;
      k_agg<<<NN, DD, 0, stream>>>(hc, offs, csr_src, agg);
      k_gru<<<dim3((NN+63)/64, 4), 256, 0, stream>>>(agg, hc, WFl, Whl, bihl, bhhl,
                                                     nmask, hn, (g == NGRUS-1) ? 1 : 0);
      unsigned short* tmp = hc; hc = hn; hn = tmp;
    }
    k_score<<<NN/4, 256, 0, stream>>>(hc, topkp + (size_t)l*DD, score);
    k_topk<<<BB, 256, 0, stream>>>(score, starts, counts, nmask);
    k_scale<<<NN, 256, 0, stream>>>(hc, score, nmask);
    k_att<<<BB, 256, 0, stream>>>(hc, gateW, gateb, starts, counts, nmask, out);
  }
}

// Round 4
// 3658.718 us; speedup vs baseline: 4.8558x; 4.8558x over previous
//
#include <hip/hip_runtime.h>
#include <hip/hip_bf16.h>

namespace {

constexpr int NN = 20000;   // nodes
constexpr int TT = 16;      // tokens per node
constexpr int DD = 256;     // hidden dim
constexpr int EE = 320000;  // edges
constexpr int BB = 64;      // graphs
constexpr int NLAY = 3;
constexpr int NGRUS = 4;
constexpr int D3 = 768;     // 3*D

typedef __bf16 bf16x8 __attribute__((ext_vector_type(8)));
typedef float  f32x4  __attribute__((ext_vector_type(4)));

__device__ __forceinline__ float us2f(unsigned short u){
  union { unsigned int i; float f; } v; v.i = ((unsigned int)u) << 16; return v.f;
}
__device__ __forceinline__ unsigned short f2us(float f){
  union { float f; unsigned int i; } v; v.f = f;
  unsigned int r = v.i + 0x7fff + ((v.i >> 16) & 1);   // RNE
  return (unsigned short)(r >> 16);
}

// ---------------- init ----------------
__global__ void k_init(int* __restrict__ deg, int* __restrict__ cursor,
                       int* __restrict__ counts, int* __restrict__ nmask,
                       float* __restrict__ out){
  int i = blockIdx.x*256 + threadIdx.x;
  if (i < NN){ deg[i] = 0; cursor[i] = 0; nmask[i] = 1; }
  if (i < BB) counts[i] = 0;
  if (i < BB*DD) out[i] = 0.f;
}

// ---------------- embedding mean-pool (f32 in -> bf16 h) ----------------
__global__ void k_embed(const int* __restrict__ xt, const float* __restrict__ emb,
                        unsigned short* __restrict__ h){
  int n = blockIdx.x; int d = threadIdx.x;
  __shared__ int toks[TT];
  if (threadIdx.x < TT) toks[threadIdx.x] = xt[n*TT + threadIdx.x];
  __syncthreads();
  float acc = 0.f; int cnt = 0;
  #pragma unroll
  for (int t = 0; t < TT; ++t){
    int tk = toks[t];
    if (tk != 0){ ++cnt; acc += emb[(size_t)tk*DD + d]; }
  }
  h[(size_t)n*DD + d] = f2us(acc / (float)(cnt > 0 ? cnt : 1));
}

// ---- WF[k][col] = sum_d W[k][d]*Wih[col][d]; store TRANSPOSED hi/lo bf16: WFT[col][k] ----
__global__ __launch_bounds__(256) void k_wf(const float* __restrict__ W,
                                            const float* __restrict__ Wih,
                                            unsigned short* __restrict__ WFThi,
                                            unsigned short* __restrict__ WFTlo){
  int lg = blockIdx.z; int l = lg / NGRUS;
  const float* A  = W   + (size_t)lg*DD*DD;   // [256][256]
  const float* Bm = Wih + (size_t)l*D3*DD;    // [768][256]
  unsigned short* oh = WFThi + (size_t)lg*D3*DD;  // [768][256]
  unsigned short* ol = WFTlo + (size_t)lg*D3*DD;
  int k0 = blockIdx.y*64, j0 = blockIdx.x*64;
  __shared__ float sA[16][68], sB[16][68];
  int tid = threadIdx.x, ty = tid/16, tx = tid%16;
  float acc[4][4] = {};
  int m = tid >> 2, dg = (tid & 3)*4;
  for (int d0 = 0; d0 < DD; d0 += 16){
    float4 ua = *reinterpret_cast<const float4*>(A  + (size_t)(k0+m)*DD + d0+dg);
    float4 ub = *reinterpret_cast<const float4*>(Bm + (size_t)(j0+m)*DD + d0+dg);
    __syncthreads();
    sA[dg+0][m]=ua.x; sA[dg+1][m]=ua.y; sA[dg+2][m]=ua.z; sA[dg+3][m]=ua.w;
    sB[dg+0][m]=ub.x; sB[dg+1][m]=ub.y; sB[dg+2][m]=ub.z; sB[dg+3][m]=ub.w;
    __syncthreads();
    #pragma unroll
    for (int dd = 0; dd < 16; ++dd){
      float a[4], b[4];
      #pragma unroll
      for (int i=0;i<4;++i) a[i] = sA[dd][ty*4+i];
      #pragma unroll
      for (int j=0;j<4;++j) b[j] = sB[dd][tx*4+j];
      #pragma unroll
      for (int i=0;i<4;++i)
        #pragma unroll
        for (int j=0;j<4;++j) acc[i][j] += a[i]*b[j];
    }
  }
  for (int i=0;i<4;++i){
    int k = k0 + ty*4 + i;
    for (int j=0;j<4;++j){
      int c = j0 + tx*4 + j;
      float v = acc[i][j];
      unsigned short hi = f2us(v);
      float rem = v - us2f(hi);
      oh[(size_t)c*DD + k] = hi;
      ol[(size_t)c*DD + k] = f2us(rem);
    }
  }
}

// ---- split Whh f32 [L][768][256] -> hi/lo bf16 same layout ----
__global__ void k_whh_split(const float* __restrict__ Whh, unsigned short* __restrict__ hi,
                            unsigned short* __restrict__ lo){
  size_t i = (size_t)blockIdx.x*256 + threadIdx.x;
  if (i >= (size_t)NLAY*D3*DD) return;
  float w = Whh[i];
  unsigned short h = f2us(w);
  hi[i] = h; lo[i] = f2us(w - us2f(h));
}

// ---------------- CSR build ----------------
__global__ void k_deg(const int* __restrict__ dst, int* __restrict__ deg){
  int e = blockIdx.x*256 + threadIdx.x; if (e < EE) atomicAdd(&deg[dst[e]], 1);
}
__global__ void k_scan(const int* __restrict__ deg, int* __restrict__ offs){
  __shared__ int part[1024];
  int t = threadIdx.x; const int CH = 20;
  int base = t*CH; int s = 0;
  for (int i = 0; i < CH; ++i){ int idx = base+i; if (idx < NN) s += deg[idx]; }
  part[t] = s; __syncthreads();
  for (int o = 1; o < 1024; o <<= 1){
    int v = part[t]; int add = (t >= o) ? part[t-o] : 0;
    __syncthreads(); part[t] = v + add; __syncthreads();
  }
  int run = (t > 0) ? part[t-1] : 0;
  for (int i = 0; i < CH; ++i){ int idx = base+i; if (idx < NN){ offs[idx] = run; run += deg[idx]; } }
  if (t == 1023) offs[NN] = run;
}
__global__ void k_fill_csr(const int* __restrict__ src, const int* __restrict__ dst,
                           const int* __restrict__ offs, int* __restrict__ cursor,
                           int* __restrict__ csr_src){
  int e = blockIdx.x*256 + threadIdx.x; if (e >= EE) return;
  int d = dst[e]; int pos = atomicAdd(&cursor[d], 1);
  csr_src[offs[d] + pos] = src[e];
}
__global__ void k_counts(const int* __restrict__ batch, int* __restrict__ counts){
  int n = blockIdx.x*256 + threadIdx.x; if (n < NN) atomicAdd(&counts[batch[n]], 1);
}
__global__ void k_starts(const int* __restrict__ counts, int* __restrict__ starts){
  if (threadIdx.x == 0){ int s = 0; for (int b = 0; b < BB; ++b){ starts[b] = s; s += counts[b]; } }
}

// ---------------- edge aggregation: agg[n] = sum_{in-edges} h[src]  (dead h == 0) ----------------
__global__ void k_agg(const unsigned short* __restrict__ h, const int* __restrict__ offs,
                      const int* __restrict__ csr_src, unsigned short* __restrict__ agg){
  int n = blockIdx.x; int d = threadIdx.x;
  int s = offs[n], e = offs[n+1];
  __shared__ int ssrc[256];
  float acc = 0.f;
  for (int base = s; base < e; base += 256){
    int mcnt = min(256, e - base);
    __syncthreads();
    if (d < mcnt) ssrc[d] = csr_src[base + d];
    __syncthreads();
    for (int i = 0; i < mcnt; ++i)
      acc += us2f(h[(size_t)ssrc[i]*DD + d]);
  }
  agg[(size_t)n*DD + d] = f2us(acc);
}

// ---------------- fused MFMA GRU step ----------------
__global__ __launch_bounds__(256) void k_gru(
    const unsigned short* __restrict__ Ag, const unsigned short* __restrict__ Ah,
    const unsigned short* __restrict__ WfH, const unsigned short* __restrict__ WfL,
    const unsigned short* __restrict__ WhH, const unsigned short* __restrict__ WhL,
    const float* __restrict__ bih, const float* __restrict__ bhh,
    const int* __restrict__ nmask, unsigned short* __restrict__ Hn, int do_relu){
  int r0 = blockIdx.x * 16;
  int wv   = threadIdx.x >> 6;
  int lane = threadIdx.x & 63;
  int lr = lane & 15;        // A row-in-tile / B col-in-tile
  int kg = lane >> 4;        // k-group
  int colbase = wv * 64;

  f32x4 accR[4], accZ[4], accNi[4], accNh[4];
  #pragma unroll
  for (int t = 0; t < 4; ++t){
    accR[t] = (f32x4){0.f,0.f,0.f,0.f}; accZ[t] = (f32x4){0.f,0.f,0.f,0.f};
    accNi[t] = (f32x4){0.f,0.f,0.f,0.f}; accNh[t] = (f32x4){0.f,0.f,0.f,0.f};
  }

  const unsigned short* agP = Ag + (size_t)(r0 + lr)*DD + kg*8;
  const unsigned short* ahP = Ah + (size_t)(r0 + lr)*DD + kg*8;
  size_t boff[4];
  #pragma unroll
  for (int ct = 0; ct < 4; ++ct)
    boff[ct] = (size_t)(colbase + ct*16 + lr)*DD + kg*8;

  constexpr size_t GZ = (size_t)256*DD;
  constexpr size_t GN = (size_t)512*DD;

  for (int kk = 0; kk < 8; ++kk){
    int kof = kk*32;
    bf16x8 aA = *reinterpret_cast<const bf16x8*>(agP + kof);
    bf16x8 aH = *reinterpret_cast<const bf16x8*>(ahP + kof);
    #pragma unroll
    for (int ct = 0; ct < 4; ++ct){
      size_t o = boff[ct] + kof;
      bf16x8 wrh = *reinterpret_cast<const bf16x8*>(WfH + o);
      bf16x8 wrl = *reinterpret_cast<const bf16x8*>(WfL + o);
      bf16x8 qrh = *reinterpret_cast<const bf16x8*>(WhH + o);
      bf16x8 qrl = *reinterpret_cast<const bf16x8*>(WhL + o);
      accR[ct] = __builtin_amdgcn_mfma_f32_16x16x32_bf16(aA, wrh, accR[ct], 0, 0, 0);
      accR[ct] = __builtin_amdgcn_mfma_f32_16x16x32_bf16(aA, wrl, accR[ct], 0, 0, 0);
      accR[ct] = __builtin_amdgcn_mfma_f32_16x16x32_bf16(aH, qrh, accR[ct], 0, 0, 0);
      accR[ct] = __builtin_amdgcn_mfma_f32_16x16x32_bf16(aH, qrl, accR[ct], 0, 0, 0);
      bf16x8 wzh = *reinterpret_cast<const bf16x8*>(WfH + o + GZ);
      bf16x8 wzl = *reinterpret_cast<const bf16x8*>(WfL + o + GZ);
      bf16x8 qzh = *reinterpret_cast<const bf16x8*>(WhH + o + GZ);
      bf16x8 qzl = *reinterpret_cast<const bf16x8*>(WhL + o + GZ);
      accZ[ct] = __builtin_amdgcn_mfma_f32_16x16x32_bf16(aA, wzh, accZ[ct], 0, 0, 0);
      accZ[ct] = __builtin_amdgcn_mfma_f32_16x16x32_bf16(aA, wzl, accZ[ct], 0, 0, 0);
      accZ[ct] = __builtin_amdgcn_mfma_f32_16x16x32_bf16(aH, qzh, accZ[ct], 0, 0, 0);
      accZ[ct] = __builtin_amdgcn_mfma_f32_16x16x32_bf16(aH, qzl, accZ[ct], 0, 0, 0);
      bf16x8 wnh = *reinterpret_cast<const bf16x8*>(WfH + o + GN);
      bf16x8 wnl = *reinterpret_cast<const bf16x8*>(WfL + o + GN);
      bf16x8 qnh = *reinterpret_cast<const bf16x8*>(WhH + o + GN);
      bf16x8 qnl = *reinterpret_cast<const bf16x8*>(WhL + o + GN);
      accNi[ct] = __builtin_amdgcn_mfma_f32_16x16x32_bf16(aA, wnh, accNi[ct], 0, 0, 0);
      accNi[ct] = __builtin_amdgcn_mfma_f32_16x16x32_bf16(aA, wnl, accNi[ct], 0, 0, 0);
      accNh[ct] = __builtin_amdgcn_mfma_f32_16x16x32_bf16(aH, qnh, accNh[ct], 0, 0, 0);
      accNh[ct] = __builtin_amdgcn_mfma_f32_16x16x32_bf16(aH, qnl, accNh[ct], 0, 0, 0);
    }
  }

  #pragma unroll
  for (int ct = 0; ct < 4; ++ct){
    int col = colbase + ct*16 + lr;
    float biR = bih[col]     + bhh[col];
    float biZ = bih[256+col] + bhh[256+col];
    float biN = bih[512+col];
    float bhN = bhh[512+col];
    #pragma unroll
    for (int j = 0; j < 4; ++j){
      int row = r0 + kg*4 + j;
      float r = 1.f/(1.f + expf(-(accR[ct][j] + biR)));
      float z = 1.f/(1.f + expf(-(accZ[ct][j] + biZ)));
      float nv = tanhf(accNi[ct][j] + biN + r*(accNh[ct][j] + bhN));
      float ho = us2f(Ah[(size_t)row*DD + col]);
      float o = (1.f - z)*nv + z*ho;
      if (do_relu) o = fmaxf(o, 0.f);
      if (!nmask[row]) o = 0.f;
      Hn[(size_t)row*DD + col] = f2us(o);
    }
  }
}

// ---------------- topk score ----------------
__global__ void k_score(const unsigned short* __restrict__ h, const float* __restrict__ p,
                        float* __restrict__ score){
  int wid = threadIdx.x >> 6, lane = threadIdx.x & 63;
  int n = blockIdx.x*4 + wid; if (n >= NN) return;
  ushort4 hu = *reinterpret_cast<const ushort4*>(h + (size_t)n*DD + lane*4);
  float4 pv = *reinterpret_cast<const float4*>(p + lane*4);
  float dot = us2f(hu.x)*pv.x + us2f(hu.y)*pv.y + us2f(hu.z)*pv.z + us2f(hu.w)*pv.w;
  float pp = pv.x*pv.x + pv.y*pv.y + pv.z*pv.z + pv.w*pv.w;
  for (int o = 32; o; o >>= 1){ dot += __shfl_down(dot, o); pp += __shfl_down(pp, o); }
  if (lane == 0) score[n] = tanhf(dot / sqrtf(pp));
}

// ---------------- per-graph topk (score desc, tie -> lower index) ----------------
__global__ void k_topk(const float* __restrict__ score, const int* __restrict__ starts,
                       const int* __restrict__ counts, int* __restrict__ nmask){
  int b = blockIdx.x; int st = starts[b]; int cnt = min(counts[b], 1024);
  __shared__ float sc[1024]; __shared__ int ired[256];
  int t = threadIdx.x;
  int myvalid = 0;
  for (int i = t; i < cnt; i += 256){
    int node = st + i; int v = nmask[node];
    sc[i] = v ? score[node] : -1e30f;
    myvalid += v;
  }
  ired[t] = myvalid; __syncthreads();
  for (int o = 128; o; o >>= 1){ if (t < o) ired[t] += ired[t+o]; __syncthreads(); }
  int nv = ired[0];
  int k = (4*nv + 4)/5;   // == ceil(0.8*nv)
  __syncthreads();
  for (int i = t; i < cnt; i += 256){
    float si = sc[i]; int node = st + i; int keep = 0;
    if (si > -1e29f){
      int rank = 0;
      for (int j = 0; j < cnt; ++j){
        float sj = sc[j];
        rank += (sj > si) || (sj == si && j < i);
      }
      keep = (rank < k);
    }
    nmask[node] = keep;
  }
}

__global__ void k_scale(unsigned short* __restrict__ h, const float* __restrict__ score,
                        const int* __restrict__ nmask){
  int idx = blockIdx.x*256 + threadIdx.x;
  int n = idx >> 8;
  unsigned short v = nmask[n] ? f2us(us2f(h[idx])*score[n]) : (unsigned short)0;
  h[idx] = v;
}

// ---------------- global attention per graph, accumulates into d_out (f32) ----------------
__global__ void k_att(const unsigned short* __restrict__ h, const float* __restrict__ gW,
                      const float* __restrict__ gb, const int* __restrict__ starts,
                      const int* __restrict__ counts, const int* __restrict__ nmask,
                      float* __restrict__ outacc){
  int b = blockIdx.x; int st = starts[b]; int cnt = min(counts[b], 1024);
  __shared__ float lg[1024]; __shared__ float red[256];
  int t = threadIdx.x, wid = t >> 6, lane = t & 63;
  float gbv = gb[0];
  for (int i = wid; i < cnt; i += 4){
    int node = st + i;
    ushort4 hu = *reinterpret_cast<const ushort4*>(h + (size_t)node*DD + lane*4);
    float4 wv = *reinterpret_cast<const float4*>(gW + lane*4);
    float dot = us2f(hu.x)*wv.x + us2f(hu.y)*wv.y + us2f(hu.z)*wv.z + us2f(hu.w)*wv.w;
    for (int o = 32; o; o >>= 1) dot += __shfl_down(dot, o);
    if (lane == 0) lg[i] = nmask[node] ? dot + gbv : -1e30f;
  }
  __syncthreads();
  float mx = -1e30f;
  for (int i = t; i < cnt; i += 256) mx = fmaxf(mx, lg[i]);
  red[t] = mx; __syncthreads();
  for (int o = 128; o; o >>= 1){ if (t < o) red[t] = fmaxf(red[t], red[t+o]); __syncthreads(); }
  mx = red[0]; __syncthreads();
  float se = 0.f;
  for (int i = t; i < cnt; i += 256){
    float e = (lg[i] > -1e29f) ? expf(lg[i] - mx) : 0.f;
    lg[i] = e; se += e;
  }
  red[t] = se; __syncthreads();
  for (int o = 128; o; o >>= 1){ if (t < o) red[t] += red[t+o]; __syncthreads(); }
  float denom = fmaxf(red[0], 1e-12f);
  __syncthreads();
  float a0=0.f,a1=0.f,a2=0.f,a3=0.f;
  int i = 0;
  for (; i + 4 <= cnt; i += 4){
    a0 += lg[i+0]*us2f(h[(size_t)(st+i+0)*DD + t]);
    a1 += lg[i+1]*us2f(h[(size_t)(st+i+1)*DD + t]);
    a2 += lg[i+2]*us2f(h[(size_t)(st+i+2)*DD + t]);
    a3 += lg[i+3]*us2f(h[(size_t)(st+i+3)*DD + t]);
  }
  for (; i < cnt; ++i) a0 += lg[i]*us2f(h[(size_t)(st+i)*DD + t]);
  outacc[(size_t)b*DD + t] += (a0+a1+a2+a3)/denom;
}

} // namespace

extern "C" void kernel_launch(void* const* d_in, const int* in_sizes, int n_in,
                              void* d_out, int out_size, void* d_ws, size_t ws_size,
                              hipStream_t stream){
  const int*   x_tokens = (const int*)d_in[0];
  const int*   e_src    = (const int*)d_in[1];
  const int*   e_dst    = e_src + EE;
  const int*   batch    = (const int*)d_in[2];
  const float* embed    = (const float*)d_in[3];
  const float* ggcW     = (const float*)d_in[4];
  const float* gWih     = (const float*)d_in[5];
  const float* gWhh     = (const float*)d_in[6];
  const float* gbih     = (const float*)d_in[7];
  const float* gbhh     = (const float*)d_in[8];
  const float* topkp    = (const float*)d_in[9];
  const float* gateW    = (const float*)d_in[10];
  const float* gateb    = (const float*)d_in[11];
  (void)in_sizes; (void)n_in; (void)out_size;
  float* out = (float*)d_out;

  char* ws = (char*)d_ws;
  size_t off = 0;
  auto carve = [&](size_t bytes)->char*{
    char* p = ws + off;
    off += (bytes + 255) & ~(size_t)255;
    return p;
  };
  unsigned short* h0    = (unsigned short*)carve((size_t)NN*DD*2);
  unsigned short* h1    = (unsigned short*)carve((size_t)NN*DD*2);
  unsigned short* agg   = (unsigned short*)carve((size_t)NN*DD*2);
  unsigned short* WFThi = (unsigned short*)carve((size_t)NLAY*NGRUS*D3*DD*2);
  unsigned short* WFTlo = (unsigned short*)carve((size_t)NLAY*NGRUS*D3*DD*2);
  unsigned short* WhhHi = (unsigned short*)carve((size_t)NLAY*D3*DD*2);
  unsigned short* WhhLo = (unsigned short*)carve((size_t)NLAY*D3*DD*2);
  float* score   = (float*)carve((size_t)NN*4);
  int* nmask     = (int*)carve((size_t)NN*4);
  int* deg       = (int*)carve((size_t)NN*4);
  int* cursor    = (int*)carve((size_t)NN*4);
  int* offs      = (int*)carve((size_t)(NN+1)*4);
  int* csr_src   = (int*)carve((size_t)EE*4);
  int* counts    = (int*)carve((size_t)BB*4);
  int* starts    = (int*)carve((size_t)BB*4);
  if (off > ws_size) return;  // ~45 MB total

  k_init<<<(NN+255)/256, 256, 0, stream>>>(deg, cursor, counts, nmask, out);
  k_embed<<<NN, DD, 0, stream>>>(x_tokens, embed, h0);
  k_wf<<<dim3(D3/64, DD/64, NLAY*NGRUS), 256, 0, stream>>>(ggcW, gWih, WFThi, WFTlo);
  k_whh_split<<<(NLAY*D3*DD + 255)/256, 256, 0, stream>>>(gWhh, WhhHi, WhhLo);
  k_deg<<<(EE+255)/256, 256, 0, stream>>>(e_dst, deg);
  k_scan<<<1, 1024, 0, stream>>>(deg, offs);
  k_fill_csr<<<(EE+255)/256, 256, 0, stream>>>(e_src, e_dst, offs, cursor, csr_src);
  k_counts<<<(NN+255)/256, 256, 0, stream>>>(batch, counts);
  k_starts<<<1, 64, 0, stream>>>(counts, starts);

  unsigned short* hc = h0; unsigned short* hn = h1;
  for (int l = 0; l < NLAY; ++l){
    const unsigned short* WhHl = WhhHi + (size_t)l*D3*DD;
    const unsigned short* WhLl = WhhLo + (size_t)l*D3*DD;
    const float* bihl = gbih + (size_t)l*D3;
    const float* bhhl = gbhh + (size_t)l*D3;
    for (int g = 0; g < NGRUS; ++g){
      const unsigned short* WfHl = WFThi + (size_t)(l*NGRUS+g)*D3*DD;
      const unsigned short* WfLl = WFTlo + (size_t)(l*NGRUS+g)*D3*DD;
      k_agg<<<NN, DD, 0, stream>>>(hc, offs, csr_src, agg);
      k_gru<<<NN/16, 256, 0, stream>>>(agg, hc, WfHl, WfLl, WhHl, WhLl, bihl, bhhl,
                                       nmask, hn, (g == NGRUS-1) ? 1 : 0);
      unsigned short* tmp = hc; hc = hn; hn = tmp;
    }
    k_score<<<NN/4, 256, 0, stream>>>(hc, topkp + (size_t)l*DD, score);
    k_topk<<<BB, 256, 0, stream>>>(score, starts, counts, nmask);
    k_scale<<<NN, 256, 0, stream>>>(hc, score, nmask);
    k_att<<<BB, 256, 0, stream>>>(hc, gateW, gateb, starts, counts, nmask, out);
  }
}

// Round 5
// 2766.414 us; speedup vs baseline: 6.4220x; 1.3225x over previous
//
#include <hip/hip_runtime.h>
#include <hip/hip_bf16.h>

namespace {

constexpr int NN = 20000;   // nodes
constexpr int TT = 16;      // tokens per node
constexpr int DD = 256;     // hidden dim
constexpr int EE = 320000;  // edges
constexpr int BB = 64;      // graphs
constexpr int NLAY = 3;
constexpr int NGRUS = 4;
constexpr int D3 = 768;     // 3*D

typedef __bf16 bf16x8 __attribute__((ext_vector_type(8)));
typedef float  f32x4  __attribute__((ext_vector_type(4)));

__device__ __forceinline__ float us2f(unsigned short u){
  union { unsigned int i; float f; } v; v.i = ((unsigned int)u) << 16; return v.f;
}
__device__ __forceinline__ unsigned short f2us(float f){
  union { float f; unsigned int i; } v; v.f = f;
  unsigned int r = v.i + 0x7fff + ((v.i >> 16) & 1);   // RNE
  return (unsigned short)(r >> 16);
}

// ---------------- init ----------------
__global__ void k_init(int* __restrict__ deg, int* __restrict__ cursor,
                       int* __restrict__ counts, int* __restrict__ nmask,
                       float* __restrict__ out){
  int i = blockIdx.x*256 + threadIdx.x;
  if (i < NN){ deg[i] = 0; cursor[i] = 0; nmask[i] = 1; }
  if (i < BB) counts[i] = 0;
  if (i < BB*DD) out[i] = 0.f;
}

// ---------------- embedding mean-pool (f32 in -> bf16 h) ----------------
__global__ void k_embed(const int* __restrict__ xt, const float* __restrict__ emb,
                        unsigned short* __restrict__ h){
  int n = blockIdx.x; int d = threadIdx.x;
  __shared__ int toks[TT];
  if (threadIdx.x < TT) toks[threadIdx.x] = xt[n*TT + threadIdx.x];
  __syncthreads();
  float acc = 0.f; int cnt = 0;
  #pragma unroll
  for (int t = 0; t < TT; ++t){
    int tk = toks[t];
    if (tk != 0){ ++cnt; acc += emb[(size_t)tk*DD + d]; }
  }
  h[(size_t)n*DD + d] = f2us(acc / (float)(cnt > 0 ? cnt : 1));
}

// ---- WF[k][col] = sum_d W[k][d]*Wih[col][d]; store TRANSPOSED hi/lo bf16: WFT[col][k] ----
__global__ __launch_bounds__(256) void k_wf(const float* __restrict__ W,
                                            const float* __restrict__ Wih,
                                            unsigned short* __restrict__ WFThi,
                                            unsigned short* __restrict__ WFTlo){
  int lg = blockIdx.z; int l = lg / NGRUS;
  const float* A  = W   + (size_t)lg*DD*DD;   // [256][256]
  const float* Bm = Wih + (size_t)l*D3*DD;    // [768][256]
  unsigned short* oh = WFThi + (size_t)lg*D3*DD;  // [768][256]
  unsigned short* ol = WFTlo + (size_t)lg*D3*DD;
  int k0 = blockIdx.y*64, j0 = blockIdx.x*64;
  __shared__ float sA[16][68], sB[16][68];
  int tid = threadIdx.x, ty = tid/16, tx = tid%16;
  float acc[4][4] = {};
  int m = tid >> 2, dg = (tid & 3)*4;
  for (int d0 = 0; d0 < DD; d0 += 16){
    float4 ua = *reinterpret_cast<const float4*>(A  + (size_t)(k0+m)*DD + d0+dg);
    float4 ub = *reinterpret_cast<const float4*>(Bm + (size_t)(j0+m)*DD + d0+dg);
    __syncthreads();
    sA[dg+0][m]=ua.x; sA[dg+1][m]=ua.y; sA[dg+2][m]=ua.z; sA[dg+3][m]=ua.w;
    sB[dg+0][m]=ub.x; sB[dg+1][m]=ub.y; sB[dg+2][m]=ub.z; sB[dg+3][m]=ub.w;
    __syncthreads();
    #pragma unroll
    for (int dd = 0; dd < 16; ++dd){
      float a[4], b[4];
      #pragma unroll
      for (int i=0;i<4;++i) a[i] = sA[dd][ty*4+i];
      #pragma unroll
      for (int j=0;j<4;++j) b[j] = sB[dd][tx*4+j];
      #pragma unroll
      for (int i=0;i<4;++i)
        #pragma unroll
        for (int j=0;j<4;++j) acc[i][j] += a[i]*b[j];
    }
  }
  for (int i=0;i<4;++i){
    int k = k0 + ty*4 + i;
    for (int j=0;j<4;++j){
      int c = j0 + tx*4 + j;
      float v = acc[i][j];
      unsigned short hi = f2us(v);
      float rem = v - us2f(hi);
      oh[(size_t)c*DD + k] = hi;
      ol[(size_t)c*DD + k] = f2us(rem);
    }
  }
}

// ---- split Whh f32 [L][768][256] -> hi/lo bf16 same layout ----
__global__ void k_whh_split(const float* __restrict__ Whh, unsigned short* __restrict__ hi,
                            unsigned short* __restrict__ lo){
  size_t i = (size_t)blockIdx.x*256 + threadIdx.x;
  if (i >= (size_t)NLAY*D3*DD) return;
  float w = Whh[i];
  unsigned short h = f2us(w);
  hi[i] = h; lo[i] = f2us(w - us2f(h));
}

// ---------------- CSR build ----------------
__global__ void k_deg(const int* __restrict__ dst, int* __restrict__ deg){
  int e = blockIdx.x*256 + threadIdx.x; if (e < EE) atomicAdd(&deg[dst[e]], 1);
}
__global__ void k_scan(const int* __restrict__ deg, int* __restrict__ offs){
  __shared__ int part[1024];
  int t = threadIdx.x; const int CH = 20;
  int base = t*CH; int s = 0;
  for (int i = 0; i < CH; ++i){ int idx = base+i; if (idx < NN) s += deg[idx]; }
  part[t] = s; __syncthreads();
  for (int o = 1; o < 1024; o <<= 1){
    int v = part[t]; int add = (t >= o) ? part[t-o] : 0;
    __syncthreads(); part[t] = v + add; __syncthreads();
  }
  int run = (t > 0) ? part[t-1] : 0;
  for (int i = 0; i < CH; ++i){ int idx = base+i; if (idx < NN){ offs[idx] = run; run += deg[idx]; } }
  if (t == 1023) offs[NN] = run;
}
__global__ void k_fill_csr(const int* __restrict__ src, const int* __restrict__ dst,
                           const int* __restrict__ offs, int* __restrict__ cursor,
                           int* __restrict__ csr_src){
  int e = blockIdx.x*256 + threadIdx.x; if (e >= EE) return;
  int d = dst[e]; int pos = atomicAdd(&cursor[d], 1);
  csr_src[offs[d] + pos] = src[e];
}
__global__ void k_counts(const int* __restrict__ batch, int* __restrict__ counts){
  int n = blockIdx.x*256 + threadIdx.x; if (n < NN) atomicAdd(&counts[batch[n]], 1);
}
__global__ void k_starts(const int* __restrict__ counts, int* __restrict__ starts){
  if (threadIdx.x == 0){ int s = 0; for (int b = 0; b < BB; ++b){ starts[b] = s; s += counts[b]; } }
}

// ---------------- edge aggregation: agg[n] = sum_{in-edges} h[src]  (dead h == 0) ----------------
__global__ void k_agg(const unsigned short* __restrict__ h, const int* __restrict__ offs,
                      const int* __restrict__ csr_src, unsigned short* __restrict__ agg){
  int n = blockIdx.x; int d = threadIdx.x;
  int s = offs[n], e = offs[n+1];
  __shared__ int ssrc[256];
  float acc = 0.f;
  for (int base = s; base < e; base += 256){
    int mcnt = min(256, e - base);
    __syncthreads();
    if (d < mcnt) ssrc[d] = csr_src[base + d];
    __syncthreads();
    for (int i = 0; i < mcnt; ++i)
      acc += us2f(h[(size_t)ssrc[i]*DD + d]);
  }
  agg[(size_t)n*DD + d] = f2us(acc);
}

// ---------------- fused MFMA GRU step (32 rows x 32 cols per wave) ----------------
// Per wave: 2 row-frags x 2 col-tiles; each weight fragment feeds 2 MFMAs (both row-frags).
__global__ __launch_bounds__(256) void k_gru(
    const unsigned short* __restrict__ Ag, const unsigned short* __restrict__ Ah,
    const unsigned short* __restrict__ WfH, const unsigned short* __restrict__ WfL,
    const unsigned short* __restrict__ WhH, const unsigned short* __restrict__ WhL,
    const float* __restrict__ bih, const float* __restrict__ bhh,
    const int* __restrict__ nmask, unsigned short* __restrict__ Hn, int do_relu){
  int r0 = blockIdx.x * 32;
  int wv   = threadIdx.x >> 6;
  int lane = threadIdx.x & 63;
  int lr = lane & 15;        // A row-in-tile / B col-in-tile
  int kg = lane >> 4;        // k-group
  int cb = blockIdx.y * 128 + wv * 32;   // this wave's col base (within 256)

  f32x4 accR[2][2], accZ[2][2], accNi[2][2], accNh[2][2];
  #pragma unroll
  for (int rf = 0; rf < 2; ++rf)
    #pragma unroll
    for (int ct = 0; ct < 2; ++ct){
      accR[rf][ct] = (f32x4){0.f,0.f,0.f,0.f}; accZ[rf][ct] = (f32x4){0.f,0.f,0.f,0.f};
      accNi[rf][ct] = (f32x4){0.f,0.f,0.f,0.f}; accNh[rf][ct] = (f32x4){0.f,0.f,0.f,0.f};
    }

  const unsigned short* agP0 = Ag + (size_t)(r0 + lr)*DD + kg*8;
  const unsigned short* agP1 = Ag + (size_t)(r0 + 16 + lr)*DD + kg*8;
  const unsigned short* ahP0 = Ah + (size_t)(r0 + lr)*DD + kg*8;
  const unsigned short* ahP1 = Ah + (size_t)(r0 + 16 + lr)*DD + kg*8;
  size_t boff[2];
  #pragma unroll
  for (int ct = 0; ct < 2; ++ct)
    boff[ct] = (size_t)(cb + ct*16 + lr)*DD + kg*8;

  constexpr size_t GZ = (size_t)256*DD;
  constexpr size_t GN = (size_t)512*DD;

  for (int kk = 0; kk < 8; ++kk){
    int kof = kk*32;
    bf16x8 aA0 = *reinterpret_cast<const bf16x8*>(agP0 + kof);
    bf16x8 aA1 = *reinterpret_cast<const bf16x8*>(agP1 + kof);
    bf16x8 aH0 = *reinterpret_cast<const bf16x8*>(ahP0 + kof);
    bf16x8 aH1 = *reinterpret_cast<const bf16x8*>(ahP1 + kof);
    #pragma unroll
    for (int ct = 0; ct < 2; ++ct){
      size_t o = boff[ct] + kof;
      bf16x8 wrh = *reinterpret_cast<const bf16x8*>(WfH + o);
      bf16x8 wrl = *reinterpret_cast<const bf16x8*>(WfL + o);
      bf16x8 qrh = *reinterpret_cast<const bf16x8*>(WhH + o);
      bf16x8 qrl = *reinterpret_cast<const bf16x8*>(WhL + o);
      accR[0][ct] = __builtin_amdgcn_mfma_f32_16x16x32_bf16(aA0, wrh, accR[0][ct], 0, 0, 0);
      accR[1][ct] = __builtin_amdgcn_mfma_f32_16x16x32_bf16(aA1, wrh, accR[1][ct], 0, 0, 0);
      accR[0][ct] = __builtin_amdgcn_mfma_f32_16x16x32_bf16(aA0, wrl, accR[0][ct], 0, 0, 0);
      accR[1][ct] = __builtin_amdgcn_mfma_f32_16x16x32_bf16(aA1, wrl, accR[1][ct], 0, 0, 0);
      accR[0][ct] = __builtin_amdgcn_mfma_f32_16x16x32_bf16(aH0, qrh, accR[0][ct], 0, 0, 0);
      accR[1][ct] = __builtin_amdgcn_mfma_f32_16x16x32_bf16(aH1, qrh, accR[1][ct], 0, 0, 0);
      accR[0][ct] = __builtin_amdgcn_mfma_f32_16x16x32_bf16(aH0, qrl, accR[0][ct], 0, 0, 0);
      accR[1][ct] = __builtin_amdgcn_mfma_f32_16x16x32_bf16(aH1, qrl, accR[1][ct], 0, 0, 0);
      bf16x8 wzh = *reinterpret_cast<const bf16x8*>(WfH + o + GZ);
      bf16x8 wzl = *reinterpret_cast<const bf16x8*>(WfL + o + GZ);
      bf16x8 qzh = *reinterpret_cast<const bf16x8*>(WhH + o + GZ);
      bf16x8 qzl = *reinterpret_cast<const bf16x8*>(WhL + o + GZ);
      accZ[0][ct] = __builtin_amdgcn_mfma_f32_16x16x32_bf16(aA0, wzh, accZ[0][ct], 0, 0, 0);
      accZ[1][ct] = __builtin_amdgcn_mfma_f32_16x16x32_bf16(aA1, wzh, accZ[1][ct], 0, 0, 0);
      accZ[0][ct] = __builtin_amdgcn_mfma_f32_16x16x32_bf16(aA0, wzl, accZ[0][ct], 0, 0, 0);
      accZ[1][ct] = __builtin_amdgcn_mfma_f32_16x16x32_bf16(aA1, wzl, accZ[1][ct], 0, 0, 0);
      accZ[0][ct] = __builtin_amdgcn_mfma_f32_16x16x32_bf16(aH0, qzh, accZ[0][ct], 0, 0, 0);
      accZ[1][ct] = __builtin_amdgcn_mfma_f32_16x16x32_bf16(aH1, qzh, accZ[1][ct], 0, 0, 0);
      accZ[0][ct] = __builtin_amdgcn_mfma_f32_16x16x32_bf16(aH0, qzl, accZ[0][ct], 0, 0, 0);
      accZ[1][ct] = __builtin_amdgcn_mfma_f32_16x16x32_bf16(aH1, qzl, accZ[1][ct], 0, 0, 0);
      bf16x8 wnh = *reinterpret_cast<const bf16x8*>(WfH + o + GN);
      bf16x8 wnl = *reinterpret_cast<const bf16x8*>(WfL + o + GN);
      bf16x8 qnh = *reinterpret_cast<const bf16x8*>(WhH + o + GN);
      bf16x8 qnl = *reinterpret_cast<const bf16x8*>(WhL + o + GN);
      accNi[0][ct] = __builtin_amdgcn_mfma_f32_16x16x32_bf16(aA0, wnh, accNi[0][ct], 0, 0, 0);
      accNi[1][ct] = __builtin_amdgcn_mfma_f32_16x16x32_bf16(aA1, wnh, accNi[1][ct], 0, 0, 0);
      accNi[0][ct] = __builtin_amdgcn_mfma_f32_16x16x32_bf16(aA0, wnl, accNi[0][ct], 0, 0, 0);
      accNi[1][ct] = __builtin_amdgcn_mfma_f32_16x16x32_bf16(aA1, wnl, accNi[1][ct], 0, 0, 0);
      accNh[0][ct] = __builtin_amdgcn_mfma_f32_16x16x32_bf16(aH0, qnh, accNh[0][ct], 0, 0, 0);
      accNh[1][ct] = __builtin_amdgcn_mfma_f32_16x16x32_bf16(aH1, qnh, accNh[1][ct], 0, 0, 0);
      accNh[0][ct] = __builtin_amdgcn_mfma_f32_16x16x32_bf16(aH0, qnl, accNh[0][ct], 0, 0, 0);
      accNh[1][ct] = __builtin_amdgcn_mfma_f32_16x16x32_bf16(aH1, qnl, accNh[1][ct], 0, 0, 0);
    }
  }

  // epilogue: C layout col=lane&15, row=(lane>>4)*4+j (within each 16x16 tile)
  #pragma unroll
  for (int rf = 0; rf < 2; ++rf){
    #pragma unroll
    for (int ct = 0; ct < 2; ++ct){
      int col = cb + ct*16 + lr;
      float biR = bih[col]     + bhh[col];
      float biZ = bih[256+col] + bhh[256+col];
      float biN = bih[512+col];
      float bhN = bhh[512+col];
      #pragma unroll
      for (int j = 0; j < 4; ++j){
        int row = r0 + rf*16 + kg*4 + j;
        float r = 1.f/(1.f + expf(-(accR[rf][ct][j] + biR)));
        float z = 1.f/(1.f + expf(-(accZ[rf][ct][j] + biZ)));
        float nv = tanhf(accNi[rf][ct][j] + biN + r*(accNh[rf][ct][j] + bhN));
        float ho = us2f(Ah[(size_t)row*DD + col]);
        float o = (1.f - z)*nv + z*ho;
        if (do_relu) o = fmaxf(o, 0.f);
        if (!nmask[row]) o = 0.f;
        Hn[(size_t)row*DD + col] = f2us(o);
      }
    }
  }
}

// ---------------- topk score ----------------
__global__ void k_score(const unsigned short* __restrict__ h, const float* __restrict__ p,
                        float* __restrict__ score){
  int wid = threadIdx.x >> 6, lane = threadIdx.x & 63;
  int n = blockIdx.x*4 + wid; if (n >= NN) return;
  ushort4 hu = *reinterpret_cast<const ushort4*>(h + (size_t)n*DD + lane*4);
  float4 pv = *reinterpret_cast<const float4*>(p + lane*4);
  float dot = us2f(hu.x)*pv.x + us2f(hu.y)*pv.y + us2f(hu.z)*pv.z + us2f(hu.w)*pv.w;
  float pp = pv.x*pv.x + pv.y*pv.y + pv.z*pv.z + pv.w*pv.w;
  for (int o = 32; o; o >>= 1){ dot += __shfl_down(dot, o); pp += __shfl_down(pp, o); }
  if (lane == 0) score[n] = tanhf(dot / sqrtf(pp));
}

// ---------------- per-graph topk (score desc, tie -> lower index) ----------------
__global__ void k_topk(const float* __restrict__ score, const int* __restrict__ starts,
                       const int* __restrict__ counts, int* __restrict__ nmask){
  int b = blockIdx.x; int st = starts[b]; int cnt = min(counts[b], 1024);
  __shared__ float sc[1024]; __shared__ int ired[256];
  int t = threadIdx.x;
  int myvalid = 0;
  for (int i = t; i < cnt; i += 256){
    int node = st + i; int v = nmask[node];
    sc[i] = v ? score[node] : -1e30f;
    myvalid += v;
  }
  ired[t] = myvalid; __syncthreads();
  for (int o = 128; o; o >>= 1){ if (t < o) ired[t] += ired[t+o]; __syncthreads(); }
  int nv = ired[0];
  int k = (4*nv + 4)/5;   // == ceil(0.8*nv)
  __syncthreads();
  for (int i = t; i < cnt; i += 256){
    float si = sc[i]; int node = st + i; int keep = 0;
    if (si > -1e29f){
      int rank = 0;
      for (int j = 0; j < cnt; ++j){
        float sj = sc[j];
        rank += (sj > si) || (sj == si && j < i);
      }
      keep = (rank < k);
    }
    nmask[node] = keep;
  }
}

__global__ void k_scale(unsigned short* __restrict__ h, const float* __restrict__ score,
                        const int* __restrict__ nmask){
  int idx = blockIdx.x*256 + threadIdx.x;
  int n = idx >> 8;
  unsigned short v = nmask[n] ? f2us(us2f(h[idx])*score[n]) : (unsigned short)0;
  h[idx] = v;
}

// ---------------- global attention per graph, accumulates into d_out (f32) ----------------
__global__ void k_att(const unsigned short* __restrict__ h, const float* __restrict__ gW,
                      const float* __restrict__ gb, const int* __restrict__ starts,
                      const int* __restrict__ counts, const int* __restrict__ nmask,
                      float* __restrict__ outacc){
  int b = blockIdx.x; int st = starts[b]; int cnt = min(counts[b], 1024);
  __shared__ float lg[1024]; __shared__ float red[256];
  int t = threadIdx.x, wid = t >> 6, lane = t & 63;
  float gbv = gb[0];
  for (int i = wid; i < cnt; i += 4){
    int node = st + i;
    ushort4 hu = *reinterpret_cast<const ushort4*>(h + (size_t)node*DD + lane*4);
    float4 wv = *reinterpret_cast<const float4*>(gW + lane*4);
    float dot = us2f(hu.x)*wv.x + us2f(hu.y)*wv.y + us2f(hu.z)*wv.z + us2f(hu.w)*wv.w;
    for (int o = 32; o; o >>= 1) dot += __shfl_down(dot, o);
    if (lane == 0) lg[i] = nmask[node] ? dot + gbv : -1e30f;
  }
  __syncthreads();
  float mx = -1e30f;
  for (int i = t; i < cnt; i += 256) mx = fmaxf(mx, lg[i]);
  red[t] = mx; __syncthreads();
  for (int o = 128; o; o >>= 1){ if (t < o) red[t] = fmaxf(red[t], red[t+o]); __syncthreads(); }
  mx = red[0]; __syncthreads();
  float se = 0.f;
  for (int i = t; i < cnt; i += 256){
    float e = (lg[i] > -1e29f) ? expf(lg[i] - mx) : 0.f;
    lg[i] = e; se += e;
  }
  red[t] = se; __syncthreads();
  for (int o = 128; o; o >>= 1){ if (t < o) red[t] += red[t+o]; __syncthreads(); }
  float denom = fmaxf(red[0], 1e-12f);
  __syncthreads();
  float a0=0.f,a1=0.f,a2=0.f,a3=0.f;
  int i = 0;
  for (; i + 4 <= cnt; i += 4){
    a0 += lg[i+0]*us2f(h[(size_t)(st+i+0)*DD + t]);
    a1 += lg[i+1]*us2f(h[(size_t)(st+i+1)*DD + t]);
    a2 += lg[i+2]*us2f(h[(size_t)(st+i+2)*DD + t]);
    a3 += lg[i+3]*us2f(h[(size_t)(st+i+3)*DD + t]);
  }
  for (; i < cnt; ++i) a0 += lg[i]*us2f(h[(size_t)(st+i)*DD + t]);
  outacc[(size_t)b*DD + t] += (a0+a1+a2+a3)/denom;
}

} // namespace

extern "C" void kernel_launch(void* const* d_in, const int* in_sizes, int n_in,
                              void* d_out, int out_size, void* d_ws, size_t ws_size,
                              hipStream_t stream){
  const int*   x_tokens = (const int*)d_in[0];
  const int*   e_src    = (const int*)d_in[1];
  const int*   e_dst    = e_src + EE;
  const int*   batch    = (const int*)d_in[2];
  const float* embed    = (const float*)d_in[3];
  const float* ggcW     = (const float*)d_in[4];
  const float* gWih     = (const float*)d_in[5];
  const float* gWhh     = (const float*)d_in[6];
  const float* gbih     = (const float*)d_in[7];
  const float* gbhh     = (const float*)d_in[8];
  const float* topkp    = (const float*)d_in[9];
  const float* gateW    = (const float*)d_in[10];
  const float* gateb    = (const float*)d_in[11];
  (void)in_sizes; (void)n_in; (void)out_size;
  float* out = (float*)d_out;

  char* ws = (char*)d_ws;
  size_t off = 0;
  auto carve = [&](size_t bytes)->char*{
    char* p = ws + off;
    off += (bytes + 255) & ~(size_t)255;
    return p;
  };
  unsigned short* h0    = (unsigned short*)carve((size_t)NN*DD*2);
  unsigned short* h1    = (unsigned short*)carve((size_t)NN*DD*2);
  unsigned short* agg   = (unsigned short*)carve((size_t)NN*DD*2);
  unsigned short* WFThi = (unsigned short*)carve((size_t)NLAY*NGRUS*D3*DD*2);
  unsigned short* WFTlo = (unsigned short*)carve((size_t)NLAY*NGRUS*D3*DD*2);
  unsigned short* WhhHi = (unsigned short*)carve((size_t)NLAY*D3*DD*2);
  unsigned short* WhhLo = (unsigned short*)carve((size_t)NLAY*D3*DD*2);
  float* score   = (float*)carve((size_t)NN*4);
  int* nmask     = (int*)carve((size_t)NN*4);
  int* deg       = (int*)carve((size_t)NN*4);
  int* cursor    = (int*)carve((size_t)NN*4);
  int* offs      = (int*)carve((size_t)(NN+1)*4);
  int* csr_src   = (int*)carve((size_t)EE*4);
  int* counts    = (int*)carve((size_t)BB*4);
  int* starts    = (int*)carve((size_t)BB*4);
  if (off > ws_size) return;  // ~45 MB total

  k_init<<<(NN+255)/256, 256, 0, stream>>>(deg, cursor, counts, nmask, out);
  k_embed<<<NN, DD, 0, stream>>>(x_tokens, embed, h0);
  k_wf<<<dim3(D3/64, DD/64, NLAY*NGRUS), 256, 0, stream>>>(ggcW, gWih, WFThi, WFTlo);
  k_whh_split<<<(NLAY*D3*DD + 255)/256, 256, 0, stream>>>(gWhh, WhhHi, WhhLo);
  k_deg<<<(EE+255)/256, 256, 0, stream>>>(e_dst, deg);
  k_scan<<<1, 1024, 0, stream>>>(deg, offs);
  k_fill_csr<<<(EE+255)/256, 256, 0, stream>>>(e_src, e_dst, offs, cursor, csr_src);
  k_counts<<<(NN+255)/256, 256, 0, stream>>>(batch, counts);
  k_starts<<<1, 64, 0, stream>>>(counts, starts);

  unsigned short* hc = h0; unsigned short* hn = h1;
  for (int l = 0; l < NLAY; ++l){
    const unsigned short* WhHl = WhhHi + (size_t)l*D3*DD;
    const unsigned short* WhLl = WhhLo + (size_t)l*D3*DD;
    const float* bihl = gbih + (size_t)l*D3;
    const float* bhhl = gbhh + (size_t)l*D3;
    for (int g = 0; g < NGRUS; ++g){
      const unsigned short* WfHl = WFThi + (size_t)(l*NGRUS+g)*D3*DD;
      const unsigned short* WfLl = WFTlo + (size_t)(l*NGRUS+g)*D3*DD;
      k_agg<<<NN, DD, 0, stream>>>(hc, offs, csr_src, agg);
      k_gru<<<dim3(NN/32, 2), 256, 0, stream>>>(agg, hc, WfHl, WfLl, WhHl, WhLl, bihl, bhhl,
                                                nmask, hn, (g == NGRUS-1) ? 1 : 0);
      unsigned short* tmp = hc; hc = hn; hn = tmp;
    }
    k_score<<<NN/4, 256, 0, stream>>>(hc, topkp + (size_t)l*DD, score);
    k_topk<<<BB, 256, 0, stream>>>(score, starts, counts, nmask);
    k_scale<<<NN, 256, 0, stream>>>(hc, score, nmask);
    k_att<<<BB, 256, 0, stream>>>(hc, gateW, gateb, starts, counts, nmask, out);
  }
}